// Round 3
// baseline (457.061 us; speedup 1.0000x reference)
//
#include <hip/hip_runtime.h>

// Trilinear grid interpolation, XCD-slab partitioned + block-local compaction.
//   velocity: [B, 3, G, G, G] f32, points: [B, N, 3] f32, bb: [3,2] f32
//   out: [B, N, 3] f32
//
// Slab partition (R1): u-axis split into 8 slabs of 16 planes (3 MB < 4 MB
// per-XCD L2); blockIdx%8 pins each slab to one XCD -> velocity read ~once.
// New (R2): each block scans a 2048-point window computing only u, ballot-
// compacts owned point indices into LDS, then gathers with ALL 64 lanes
// active (R1 ran gathers at 1/8 lane efficiency). LDS cap = 2048 entries =
// worst case (all points in one slab) -> correct for any input.

constexpr int G = 128;
constexpr long long G3 = (long long)G * G * G;
constexpr int NSLAB = 8;          // == #XCDs
constexpr int SCAN_ITERS = 8;     // 8 x 256 threads = 2048-point window
constexpr int WIN = SCAN_ITERS * 256;

__global__ __launch_bounds__(256) void trilerp_compact_kernel(
    const float* __restrict__ vel,   // [B,3,G,G,G]
    const float* __restrict__ pts,   // [B,N,3]
    const float* __restrict__ bb,    // [3,2]
    float* __restrict__ out,         // [B,N,3]
    int N, int nwin)
{
    __shared__ int s_idx[WIN];
    __shared__ int s_cnt;

    int bid  = blockIdx.x;
    int slab = bid & (NSLAB - 1);
    int t    = bid >> 3;
    int cw   = t % nwin;             // point window within batch
    int b    = t / nwin;             // batch

    if (threadIdx.x == 0) s_cnt = 0;
    __syncthreads();

    float bx0 = bb[0], bx1 = bb[1];
    float by0 = bb[2], by1 = bb[3];
    float bz0 = bb[4], bz1 = bb[5];
    const float Gm1 = (float)(G - 1);
    float sx = Gm1 / (bx1 - bx0);
    float sy = Gm1 / (by1 - by0);
    float sz = Gm1 / (bz1 - bz0);

    int lane = threadIdx.x & 63;
    long long pbase = (long long)b * N;

    // ---- phase A: scan window, compact owned indices into LDS ----
    int n0 = cw * WIN + threadIdx.x;
    #pragma unroll
    for (int it = 0; it < SCAN_ITERS; ++it) {
        int n = n0 + it * 256;
        bool own = false;
        if (n < N) {
            float px = pts[(pbase + n) * 3];
            float u = (px - bx0) * sx;
            float fu = fminf(fmaxf(floorf(u), 0.f), Gm1);
            int iu = (int)fu;
            own = ((iu >> 4) == slab);
        }
        unsigned long long mask = __ballot(own);
        int cnt = __popcll(mask);
        int base = 0;
        if (lane == 0 && cnt) base = atomicAdd(&s_cnt, cnt);
        base = __shfl(base, 0);
        if (own) {
            int pos = base + __popcll(mask & ((1ull << lane) - 1));
            s_idx[pos] = n;
        }
    }
    __syncthreads();

    // ---- phase B: full-lane gathers over compacted list ----
    int total = s_cnt;
    const float* vb = vel + (long long)b * 3 * G3;

    for (int i = threadIdx.x; i < total; i += 256) {
        int n = s_idx[i];
        const float* p = pts + (pbase + n) * 3;   // L1-hot (window just scanned)
        float px = p[0], py = p[1], pz = p[2];

        float u = (px - bx0) * sx;
        float v = (py - by0) * sy;
        float w = (pz - bz0) * sz;

        float fu = fminf(fmaxf(floorf(u), 0.f), Gm1);
        float fv = fminf(fmaxf(floorf(v), 0.f), Gm1);
        float fw = fminf(fmaxf(floorf(w), 0.f), Gm1);

        float du = u - fu, dv = v - fv, dw = w - fw;   // frac
        float gu = fu + 1.0f - u;                      // gfrac
        float gv = fv + 1.0f - v;
        float gw = fw + 1.0f - w;

        int iu1 = (int)fu, iv1 = (int)fv, iw1 = (int)fw;
        int iu2 = min(iu1 + 1, G - 1);
        int iv2 = min(iv1 + 1, G - 1);
        int iw2 = min(iw1 + 1, G - 1);

        float w11 = gu * gv, w12 = gu * dv, w21 = du * gv, w22 = du * dv;

        float o[3];
        #pragma unroll
        for (int ch = 0; ch < 3; ++ch) {
            const float* vc = vb + (long long)ch * G3;
            const float* r11 = vc + ((iu1 << 7) + iv1) * G;
            const float* r12 = vc + ((iu1 << 7) + iv2) * G;
            const float* r21 = vc + ((iu2 << 7) + iv1) * G;
            const float* r22 = vc + ((iu2 << 7) + iv2) * G;
            o[ch] = w11 * (gw * r11[iw1] + dw * r11[iw2])
                  + w12 * (gw * r12[iw1] + dw * r12[iw2])
                  + w21 * (gw * r21[iw1] + dw * r21[iw2])
                  + w22 * (gw * r22[iw1] + dw * r22[iw2]);
        }

        float* op = out + (pbase + n) * 3;
        op[0] = o[0]; op[1] = o[1]; op[2] = o[2];
    }
}

extern "C" void kernel_launch(void* const* d_in, const int* in_sizes, int n_in,
                              void* d_out, int out_size, void* d_ws, size_t ws_size,
                              hipStream_t stream) {
    const float* vel = (const float*)d_in[0];
    const float* pts = (const float*)d_in[1];
    const float* bb  = (const float*)d_in[2];
    float* out = (float*)d_out;

    int B = (int)(in_sizes[0] / (3 * G3));       // 16
    int N = in_sizes[1] / (3 * B);               // 200000

    int nwin = (N + WIN - 1) / WIN;              // 98
    long long total_blocks = (long long)B * nwin * NSLAB;  // 12544
    trilerp_compact_kernel<<<(int)total_blocks, 256, 0, stream>>>(vel, pts, bb, out, N, nwin);
}

// Round 4
// 319.939 us; speedup vs baseline: 1.4286x; 1.4286x over previous
//
#include <hip/hip_runtime.h>

// Trilinear grid interpolation, XCD-slab partitioned + float2 w-pair gathers.
//   velocity: [B, 3, G, G, G] f32, points: [B, N, 3] f32, bb: [3,2] f32
//   out: [B, N, 3] f32
//
// R1 lesson: slab->XCD L2 pinning cuts HBM fetch 4.4x (2.1GB -> 475MB).
// R2 lesson: gather cost is per-ADDRESS L1 transactions, not per-instruction;
//   lane-compaction doesn't reduce transactions and its scan overhead regressed.
// R3: halve the address count — the two w-taps are adjacent, load as one
//   float2 (12 gathers/point instead of 24). Edge iw1==G-1 handled by loading
//   at min(iw1,G-2) and selecting .y for both taps.

constexpr int G = 128;
constexpr long long G3 = (long long)G * G * G;
constexpr int NSLAB = 8;   // == #XCDs

__global__ __launch_bounds__(256) void trilerp_pair_kernel(
    const float* __restrict__ vel,   // [B,3,G,G,G]
    const float* __restrict__ pts,   // [B,N,3]
    const float* __restrict__ bb,    // [3,2]
    float* __restrict__ out,         // [B,N,3]
    int N, int nchunk)
{
    int bid  = blockIdx.x;
    int slab = bid & (NSLAB - 1);
    int t    = bid >> 3;
    int c    = t % nchunk;           // chunk within batch
    int b    = t / nchunk;           // batch

    int n = c * 256 + threadIdx.x;
    if (n >= N) return;

    float bx0 = bb[0], bx1 = bb[1];
    float by0 = bb[2], by1 = bb[3];
    float bz0 = bb[4], bz1 = bb[5];

    long long pi = (long long)b * N + n;
    const float* p = pts + pi * 3;
    float px = p[0], py = p[1], pz = p[2];

    const float Gm1 = (float)(G - 1);
    float u = (px - bx0) / (bx1 - bx0) * Gm1;

    float fu = fminf(fmaxf(floorf(u), 0.f), Gm1);
    int iu1 = (int)fu;
    if ((iu1 >> 4) != slab) return;   // not this XCD's slab

    float v = (py - by0) / (by1 - by0) * Gm1;
    float w = (pz - bz0) / (bz1 - bz0) * Gm1;
    float fv = fminf(fmaxf(floorf(v), 0.f), Gm1);
    float fw = fminf(fmaxf(floorf(w), 0.f), Gm1);

    float du = u - fu, dv = v - fv, dw = w - fw;   // frac
    float gu = fu + 1.0f - u;                      // gfrac
    float gv = fv + 1.0f - v;
    float gw = fw + 1.0f - w;

    int iv1 = (int)fv, iw1 = (int)fw;
    int iu2 = min(iu1 + 1, G - 1);
    int iv2 = min(iv1 + 1, G - 1);

    int iwb = min(iw1, G - 2);        // float2 base along w
    bool lo = (iw1 <= G - 2);         // tap1 = lo ? .x : .y ; tap2 always .y

    float w11 = gu * gv, w12 = gu * dv, w21 = du * gv, w22 = du * dv;

    const float* vb = vel + (long long)b * 3 * G3;

    long long o11 = (long long)((iu1 << 7) + iv1) * G + iwb;
    long long o12 = (long long)((iu1 << 7) + iv2) * G + iwb;
    long long o21 = (long long)((iu2 << 7) + iv1) * G + iwb;
    long long o22 = (long long)((iu2 << 7) + iv2) * G + iwb;

    float o[3];
    #pragma unroll
    for (int ch = 0; ch < 3; ++ch) {
        const float* vc = vb + (long long)ch * G3;
        float2 p11 = *reinterpret_cast<const float2*>(vc + o11);
        float2 p12 = *reinterpret_cast<const float2*>(vc + o12);
        float2 p21 = *reinterpret_cast<const float2*>(vc + o21);
        float2 p22 = *reinterpret_cast<const float2*>(vc + o22);
        float a11 = lo ? p11.x : p11.y;
        float a12 = lo ? p12.x : p12.y;
        float a21 = lo ? p21.x : p21.y;
        float a22 = lo ? p22.x : p22.y;
        o[ch] = w11 * (gw * a11 + dw * p11.y)
              + w12 * (gw * a12 + dw * p12.y)
              + w21 * (gw * a21 + dw * p21.y)
              + w22 * (gw * a22 + dw * p22.y);
    }

    float* op = out + pi * 3;
    op[0] = o[0]; op[1] = o[1]; op[2] = o[2];
}

extern "C" void kernel_launch(void* const* d_in, const int* in_sizes, int n_in,
                              void* d_out, int out_size, void* d_ws, size_t ws_size,
                              hipStream_t stream) {
    const float* vel = (const float*)d_in[0];
    const float* pts = (const float*)d_in[1];
    const float* bb  = (const float*)d_in[2];
    float* out = (float*)d_out;

    int B = (int)(in_sizes[0] / (3 * G3));       // 16
    int N = in_sizes[1] / (3 * B);               // 200000

    int nchunk = (N + 255) / 256;                // 782
    long long total_blocks = (long long)B * nchunk * NSLAB;  // 100096
    trilerp_pair_kernel<<<(int)total_blocks, 256, 0, stream>>>(vel, pts, bb, out, N, nchunk);
}